// Round 1
// baseline (959.174 us; speedup 1.0000x reference)
//
#include <hip/hip_runtime.h>
#include <math.h>

// Problem constants (from reference):
constexpr int Bc = 4, Tc = 512, Cc = 768, Hc = 12, HSc = 64;
constexpr int QKVN = 3 * Cc;  // 2304
constexpr double EPSd = 1e-6;

// ---------------------------------------------------------------------------
// Row-tiled GEMM with fp64 accumulation: out[r0..r0+7, :] = X rows @ W + bias.
// Grid: (rows/8, N/256), block 256. W streamed coalesced; X rows in LDS.
// fp64 accumulate so stored fp32 q,k,v (and final out) are correctly rounded —
// the DPP decisions downstream are comparison cascades; accumulation error
// would flip selections and blow the absmax threshold.
// ---------------------------------------------------------------------------
__global__ void __launch_bounds__(256) gemm8_kernel(
    const float* __restrict__ X, const float* __restrict__ W,
    const float* __restrict__ bias, float* __restrict__ outp, int N) {
  __shared__ float xs[8][Cc];
  const int r0 = blockIdx.x * 8;
  const int o = blockIdx.y * 256 + threadIdx.x;
  for (int idx = threadIdx.x; idx < 8 * Cc; idx += 256) {
    const int r = idx / Cc, c = idx % Cc;
    xs[r][c] = X[(size_t)(r0 + r) * Cc + c];
  }
  __syncthreads();
  const double b = (double)bias[o];
  double acc[8];
#pragma unroll
  for (int r = 0; r < 8; ++r) acc[r] = b;
  for (int c = 0; c < Cc; ++c) {
    const double w = (double)W[(size_t)c * N + o];
#pragma unroll
    for (int r = 0; r < 8; ++r) acc[r] += (double)xs[r][c] * w;
  }
#pragma unroll
  for (int r = 0; r < 8; ++r) outp[(size_t)(r0 + r) * N + o] = (float)acc[r];
}

// ---------------------------------------------------------------------------
// Greedy DPP selection: one 64-thread block (one wave) per (b,h,t) token.
// qkv layout: [B*T][2304] with q at +0, k at +768, v at +1536, head h at +h*64.
// All selection math in fp64 to match an fp64 numpy reference's decisions.
// ---------------------------------------------------------------------------
__global__ void __launch_bounds__(64) select_kernel(
    const float* __restrict__ qkv, float* __restrict__ y) {
  const int bid = blockIdx.x;  // bh*T + i
  const int i = bid % Tc;
  const int bh = bid / Tc;
  const int b = bh / Hc;
  const int h = bh % Hc;
  const int lane = threadIdx.x;

  const float* base = qkv + (size_t)b * Tc * QKVN + h * HSc;
  const float* qrow = base + (size_t)i * QKVN;
  const float* kbase = base + Cc;       // k row j at kbase + j*QKVN
  const float* vbase = base + 2 * Cc;   // v row j at vbase + j*QKVN

  __shared__ double qis[HSc];
  __shared__ double g0[8][8];        // gram of selected set
  __shared__ double crossm[16][9];   // cross[m][a] = k_cand[m] . k_sel[a] (padded)
  __shared__ double Amat[16][65];    // per-candidate LU scratch (stride-65 pad)
  __shared__ double cnorm[16];
  __shared__ int topidxS[16];
  __shared__ int selS[8];

  qis[lane] = (double)qrow[lane];
  __syncthreads();

  // ---- sims: sim[j] = k_j . q_i for j<=i else -inf; 8 j's per lane ----
  double sim[8];
#pragma unroll
  for (int jj = 0; jj < 8; ++jj) {
    const int j = jj * 64 + lane;
    double s = -INFINITY;
    if (j <= i) {
      const float4* kr = reinterpret_cast<const float4*>(kbase + (size_t)j * QKVN);
      double acc = 0.0;
#pragma unroll
      for (int dq = 0; dq < HSc / 4; ++dq) {
        const float4 kv = kr[dq];
        acc += (double)kv.x * qis[dq * 4 + 0];
        acc += (double)kv.y * qis[dq * 4 + 1];
        acc += (double)kv.z * qis[dq * 4 + 2];
        acc += (double)kv.w * qis[dq * 4 + 3];
      }
      s = acc;
    }
    sim[jj] = s;
  }

  // ---- top-16, descending, ties -> lower index (jax.lax.top_k semantics) ----
  unsigned taken = 0;  // per-lane bitmask over jj
  unsigned avail = 0;  // uniform 16-bit candidate availability
  for (int m = 0; m < 16; ++m) {
    double bv = -INFINITY;
    int bj = Tc;  // sentinel larger than any index
#pragma unroll
    for (int jj = 0; jj < 8; ++jj) {
      const int j = jj * 64 + lane;
      if (!((taken >> jj) & 1u)) {
        const double val = sim[jj];
        if (val > bv || (val == bv && j < bj)) { bv = val; bj = j; }
      }
    }
#pragma unroll
    for (int off = 32; off >= 1; off >>= 1) {
      const double ov = __shfl_down(bv, off);
      const int oj = __shfl_down(bj, off);
      if (ov > bv || (ov == bv && oj < bj)) { bv = ov; bj = oj; }
    }
    bv = __shfl(bv, 0);
    bj = __shfl(bj, 0);
    if (lane == 0) topidxS[m] = bj;
    if ((bj & 63) == lane) taken |= (1u << (bj >> 6));
    // avail: isfinite(val) && idx != i   (sims can't be +inf/NaN here)
    if (bv > -INFINITY && bj != i) avail |= (1u << m);
  }
  __syncthreads();

  // ---- candidate norms and cross[:,0] (vs k_i, slot 0 of selection) ----
  if (lane < 16) {
    const float* kc = kbase + (size_t)topidxS[lane] * QKVN;
    const float* ki = kbase + (size_t)i * QKVN;
    double nrm = 0.0, c0 = 0.0;
#pragma unroll
    for (int d = 0; d < HSc; ++d) {
      const double kv = (double)kc[d];
      nrm += kv * kv;
      c0 += kv * (double)ki[d];
    }
    cnorm[lane] = nrm;
    crossm[lane][0] = c0;
  }

  // ---- k_i . k_i ----
  double kii;
  {
    const double t = (double)kbase[(size_t)i * QKVN + lane];
    double sq = t * t;
#pragma unroll
    for (int off = 32; off >= 1; off >>= 1) sq += __shfl_down(sq, off);
    kii = __shfl(sq, 0);
  }
  if (lane == 0) { g0[0][0] = kii; selS[0] = i; }
  double cur_s = -log(kii + EPSd);
  int count = 1;
  __syncthreads();

  // ---- greedy loop: up to 7 additions ----
  for (int it = 0; it < 7; ++it) {
    double sorig = -INFINITY;
    if (lane < 16 && ((avail >> lane) & 1u)) {
      const int n = count + 1;
      double* A = Amat[lane];
      for (int a = 0; a < count; ++a) {
        for (int bb = 0; bb < count; ++bb) A[a * 8 + bb] = g0[a][bb];
        const double cv = crossm[lane][a];
        A[count * 8 + a] = cv;
        A[a * 8 + count] = cv;
      }
      A[count * 8 + count] = cnorm[lane];
      // LAPACK-style LU with partial pivoting (first max, reciprocal scaling)
      double det = 1.0;
      for (int p = 0; p < n; ++p) {
        int piv = p;
        double mx = fabs(A[p * 8 + p]);
        for (int r = p + 1; r < n; ++r) {
          const double ar = fabs(A[r * 8 + p]);
          if (ar > mx) { mx = ar; piv = r; }
        }
        if (piv != p) {
          for (int c = 0; c < n; ++c) {
            const double t2 = A[p * 8 + c];
            A[p * 8 + c] = A[piv * 8 + c];
            A[piv * 8 + c] = t2;
          }
          det = -det;
        }
        const double dpp = A[p * 8 + p];
        det *= dpp;
        if (dpp != 0.0) {
          const double inv = 1.0 / dpp;
          for (int r = p + 1; r < n; ++r) {
            const double f = A[r * 8 + p] * inv;
            for (int c = p + 1; c < n; ++c) A[r * 8 + c] -= f * A[p * 8 + c];
          }
        }
      }
      sorig = -log(det + EPSd) / (double)n;
    }
    // argmax over candidates; NaN acts as max (numpy argmax), ties -> lower m
    double bkey = (lane < 16) ? (__builtin_isnan(sorig) ? INFINITY : sorig)
                              : -INFINITY;
    int bm = lane;
#pragma unroll
    for (int off = 32; off >= 1; off >>= 1) {
      const double ok2 = __shfl_down(bkey, off);
      const int om = __shfl_down(bm, off);
      if (ok2 > bkey || (ok2 == bkey && om < bm)) { bkey = ok2; bm = om; }
    }
    bm = __shfl(bm, 0);
    const double best_s = __shfl(sorig, bm);  // original (possibly NaN) value
    const bool accept = (avail != 0u) && ((best_s > cur_s) || (count < 2));
    if (!accept) break;  // uniform across the wave
    const int bestIdx = topidxS[bm];
    __syncthreads();
    if (lane < count) {
      const double cv = crossm[bm][lane];
      g0[count][lane] = cv;
      g0[lane][count] = cv;
    }
    if (lane == 0) {
      g0[count][count] = cnorm[bm];
      selS[count] = bestIdx;
    }
    if (lane < 16) {
      const float* ka = kbase + (size_t)topidxS[lane] * QKVN;
      const float* kb = kbase + (size_t)bestIdx * QKVN;
      double acc = 0.0;
#pragma unroll
      for (int d = 0; d < HSc; ++d) acc += (double)ka[d] * (double)kb[d];
      crossm[lane][count] = acc;
    }
    avail &= ~(1u << bm);
    cur_s = best_s;
    ++count;
    __syncthreads();
  }
  __syncthreads();

  // ---- output: mean of selected v rows; y layout [B,T,H,HS] = [B,T,C] ----
  double acc = 0.0;
  for (int a = 0; a < count; ++a)
    acc += (double)vbase[(size_t)selS[a] * QKVN + lane];
  y[(((size_t)b * Tc + i) * Hc + h) * HSc + lane] = (float)(acc / (double)count);
}

// ---------------------------------------------------------------------------
extern "C" void kernel_launch(void* const* d_in, const int* in_sizes, int n_in,
                              void* d_out, int out_size, void* d_ws, size_t ws_size,
                              hipStream_t stream) {
  (void)in_sizes; (void)n_in; (void)out_size; (void)ws_size;
  const float* x  = (const float*)d_in[0];
  const float* Wa = (const float*)d_in[1];
  const float* ba = (const float*)d_in[2];
  const float* Wp = (const float*)d_in[3];
  const float* bp = (const float*)d_in[4];
  float* out = (float*)d_out;

  float* qkv = (float*)d_ws;                        // [B*T][2304] fp32
  float* y   = qkv + (size_t)Bc * Tc * QKVN;        // [B*T][768]  fp32

  // 1) qkv = x @ W_attn + b_attn   (fp64 accumulate, fp32 store)
  hipLaunchKernelGGL(gemm8_kernel, dim3((Bc * Tc) / 8, QKVN / 256), dim3(256), 0,
                     stream, x, Wa, ba, qkv, QKVN);
  // 2) greedy DPP per (b,h,t); writes y [B,T,C]
  hipLaunchKernelGGL(select_kernel, dim3(Bc * Hc * Tc), dim3(64), 0, stream, qkv, y);
  // 3) out = y @ W_proj + b_proj
  hipLaunchKernelGGL(gemm8_kernel, dim3((Bc * Tc) / 8, Cc / 256), dim3(256), 0,
                     stream, y, Wp, bp, out, Cc);
}